// Round 6
// baseline (232.626 us; speedup 1.0000x reference)
//
#include <hip/hip_runtime.h>

// ScRRAMBLe capsule layer — R9: transform via global_load_lds conveyor.
//   xr[k,m] = sum_ij Ci[ij, c, k] * x[ij, m]          (route, per capsule c)
//   y[c,j,l] = sum_{k,m} Wi[c,j,k,l,m] * xr[k,m]      (transform)
//
// R8 post-mortem: kernel ~80us (inferred; fell below top-5 cutoff with
// overhead pinned at 143.8us from R5). VGPR=88 << the >=160 the phase-2
// register double-buffer needs -> compiler REFUSED it and re-batched with
// drains: transform has been latency-bound (~55-60us, 2.3TB/s) in every
// register-buffered variant. R9: stream Wi with global_load_lds width=16
// (zero VGPR cost, compiler can't collapse) + counted vmcnt waits (T4).
// 16KB/wave outstanding x 8 waves = 128KB/CU >> ~20KB BW-delay product.
// Predicted: kernel ~40us, total ~185us, FETCH ~134MB, LDS 64KB, VGPR~60.
//
// LDS 64KB phase-aliased: route uses part[0,1KB)+ci_s[4KB,36KB);
// transform uses wi[4 waves][2 bufs][8KB] = whole 64KB. Barriers separate.

typedef float f4 __attribute__((ext_vector_type(4)));

#define GLDS16(gsrc, ldst)                                                   \
    __builtin_amdgcn_global_load_lds(                                        \
        (const __attribute__((address_space(1))) unsigned int*)(gsrc),       \
        (__attribute__((address_space(3))) unsigned int*)(ldst), 16, 0, 0)

#define VMW(n) asm volatile("s_waitcnt vmcnt(" #n ")" ::: "memory")

__global__ __launch_bounds__(256, 2) void fused_caps_kernel(
    const float* __restrict__ x,
    const float* __restrict__ Ci,
    const float* __restrict__ Wi,
    float* __restrict__ y)
{
    const int c    = blockIdx.x;
    const int t    = threadIdx.x;
    const int w    = t >> 6;          // phase1: ij subgroup; phase2: j
    const int lane = t & 63;
    const int lq   = lane >> 4;
    const int m16  = lane & 15;

    const f4* __restrict__ Ci4 = (const f4*)Ci;

    __shared__ f4 lds[4096];          // 64 KB

    f4*    ci_s  = lds + 256;         // [4KB, 36KB): Ci column (2048 f4)
    float* partf = (float*)lds;       // [0, 4KB): cross-wave reduce

    // ---- Stage Ci column -> LDS: 8 lane-parallel gathers per thread ----
    {
        f4 cv[8];
        #pragma unroll
        for (int u = 0; u < 8; ++u)
            cv[u] = Ci4[(t + (u << 8)) * 512 + c];   // 64 distinct lines/instr
        #pragma unroll
        for (int u = 0; u < 8; ++u)
            ci_s[t + (u << 8)] = cv[u];
    }
    __syncthreads();

    // ---- Phase 1: route; wave w owns ij in [w*512, w*512+512) ----
    f4 acc = {0.f, 0.f, 0.f, 0.f};
    {
        const int ij0 = w << 9;
        const float* __restrict__ xp = x + lane;
        for (int it = 0; it < 512; it += 16) {
            float xv[16];
            #pragma unroll
            for (int u = 0; u < 16; ++u)
                xv[u] = xp[(ij0 + it + u) << 6];     // 256B coalesced, cached
            #pragma unroll
            for (int u = 0; u < 16; ++u)
                acc += ci_s[ij0 + it + u] * xv[u];   // LDS broadcast read
        }
    }
    // part[0,1KB) does not overlap ci_s -> safe to write before barrier
    partf[(w << 8) +   0 + lane] = acc.x;
    partf[(w << 8) +  64 + lane] = acc.y;
    partf[(w << 8) + 128 + lane] = acc.z;
    partf[(w << 8) + 192 + lane] = acc.w;
    __syncthreads();

    // Cross-wave reduce: xr[k] as f4 over this lane's m16 quad.
    const f4* partf4 = (const f4*)partf;
    f4 xr0 = partf4[  0 + m16] + partf4[ 64 + m16] + partf4[128 + m16] + partf4[192 + m16];
    f4 xr1 = partf4[ 16 + m16] + partf4[ 80 + m16] + partf4[144 + m16] + partf4[208 + m16];
    f4 xr2 = partf4[ 32 + m16] + partf4[ 96 + m16] + partf4[160 + m16] + partf4[224 + m16];
    f4 xr3 = partf4[ 48 + m16] + partf4[112 + m16] + partf4[176 + m16] + partf4[240 + m16];
    __syncthreads();   // all part reads done before wi staging overwrites lds

    // ---- Phase 2: Wi conveyor. Wave w = j. 8 tiles x 8KB, 2 LDS bufs. ----
    // Tile tt: g4 = tt>>1 (l-group of 16), half = tt&1 (8-l subrange).
    //   l(tt, c2b, lq) = (g4<<4) + (half<<3) + (c2b<<2) + lq
    // Tile LDS layout [k 4][c2b 2][lane 64] f4 at lds[w*1024 + buf*512].
    // Each GLDS16: 64 lanes x 16B = 1KB contiguous global (4 l-rows x 256B).
    const float* __restrict__ WfB = Wi + ((size_t)((c << 2) + w) << 14);

#define STAGE(buf, tt)                                                       \
    _Pragma("unroll")                                                        \
    for (int k = 0; k < 4; ++k) {                                            \
        _Pragma("unroll")                                                    \
        for (int c2b = 0; c2b < 2; ++c2b) {                                  \
            const int l = (((tt) >> 1) << 4) + (((tt) & 1) << 3)             \
                        + (c2b << 2) + lq;                                   \
            GLDS16(WfB + (k << 12) + (l << 6) + (m16 << 2),                  \
                   &lds[(w << 10) + ((buf) << 9) + (((k << 1) + c2b) << 6)]);\
        }                                                                    \
    }

#define COMPUTE(buf, tt)                                                     \
    _Pragma("unroll")                                                        \
    for (int c2b = 0; c2b < 2; ++c2b) {                                      \
        const f4* tb = lds + (w << 10) + ((buf) << 9);                       \
        f4 s = tb[((0 << 1) + c2b) * 64 + lane] * xr0                        \
             + tb[((1 << 1) + c2b) * 64 + lane] * xr1                        \
             + tb[((2 << 1) + c2b) * 64 + lane] * xr2                        \
             + tb[((3 << 1) + c2b) * 64 + lane] * xr3;                       \
        float p = s.x + s.y + s.z + s.w;                                     \
        p += __shfl_xor(p, 1);                                               \
        p += __shfl_xor(p, 2);                                               \
        p += __shfl_xor(p, 4);                                               \
        p += __shfl_xor(p, 8);                                               \
        if (m16 == 0)                                                        \
            y[(((c << 2) + w) << 6) + (((tt) >> 1) << 4)                     \
              + (((tt) & 1) << 3) + (c2b << 2) + lq] = p;                    \
    }

    STAGE(0, 0)
    STAGE(1, 1)
    VMW(8); COMPUTE(0, 0) STAGE(0, 2)
    VMW(8); COMPUTE(1, 1) STAGE(1, 3)
    VMW(8); COMPUTE(0, 2) STAGE(0, 4)
    VMW(8); COMPUTE(1, 3) STAGE(1, 5)
    VMW(8); COMPUTE(0, 4) STAGE(0, 6)
    VMW(8); COMPUTE(1, 5) STAGE(1, 7)
    VMW(8); COMPUTE(0, 6)
    VMW(0); COMPUTE(1, 7)

#undef STAGE
#undef COMPUTE
}

extern "C" void kernel_launch(void* const* d_in, const int* in_sizes, int n_in,
                              void* d_out, int out_size, void* d_ws, size_t ws_size,
                              hipStream_t stream) {
    const float* x  = (const float*)d_in[0];   // 131072 floats
    const float* Ci = (const float*)d_in[1];   // 2048 * 512 * 4 floats (16 MB)
    const float* Wi = (const float*)d_in[2];   // 512*4*4*64*64 floats (134 MB)
    float* y = (float*)d_out;                  // 512*4*64 floats

    fused_caps_kernel<<<512, 256, 0, stream>>>(x, Ci, Wi, y);
}